// Round 7
// baseline (1020.413 us; speedup 1.0000x reference)
//
#include <hip/hip_runtime.h>
#include <hip/hip_bf16.h>

#define Bsz  16384
#define Din  1024
#define Dout 1024
#define Hdim 2048
#define Ecnt 8
#define CNT_PAD 32   // pad expert counters to 128 B apart

typedef _Float16 f16;
typedef _Float16 f16x8 __attribute__((ext_vector_type(8)));
typedef _Float16 f16x4 __attribute__((ext_vector_type(4)));
typedef float    f32x4 __attribute__((ext_vector_type(4)));

#define AS_GLOBAL __attribute__((address_space(1)))
#define AS_LDS    __attribute__((address_space(3)))

__device__ __forceinline__ void async_copy16(const void* gptr, void* lptr) {
    __builtin_amdgcn_global_load_lds(
        (const AS_GLOBAL unsigned int*)gptr,
        (AS_LDS unsigned int*)lptr, 16, 0, 0);
}

// ---------------- fp32 -> fp16 cast ----------------
__global__ __launch_bounds__(256) void cast_kernel(
    const float* __restrict__ in, f16* __restrict__ out)
{
    int i = (blockIdx.x * 256 + threadIdx.x) * 4;
    float4 v = *(const float4*)(in + i);
    f16x4 o;
    o.x = (f16)v.x; o.y = (f16)v.y; o.z = (f16)v.z; o.w = (f16)v.w;
    *(f16x4*)(out + i) = o;
}

// ---------------- Router: logits -> softmax -> top-2 -> buckets ----------------
__global__ __launch_bounds__(256) void router_kernel(
    const float* __restrict__ x, const float* __restrict__ rW,
    const float* __restrict__ rb, float* __restrict__ probs_out,
    int* __restrict__ cnt, int* __restrict__ bucket, float* __restrict__ gates)
{
    __shared__ float s_rw[Ecnt * Din];   // 32 KiB
    __shared__ int   s_e[64];
    __shared__ float s_g[64];
    __shared__ int   s_lpos[64];
    __shared__ int   s_lcnt[Ecnt];
    __shared__ int   s_base[Ecnt];

    int t = threadIdx.x;
    if (t < Ecnt) s_lcnt[t] = 0;
    for (int i = t; i < Ecnt * Din; i += 256) s_rw[i] = rW[i];
    __syncthreads();

    int wid = t >> 6, lane = t & 63;

    float rbv[8];
    #pragma unroll
    for (int e = 0; e < 8; e++) rbv[e] = rb[e];

    #pragma unroll 2
    for (int tt = 0; tt < 8; tt++) {
        int li = wid * 8 + tt;
        int token = blockIdx.x * 32 + li;
        const float* xrow = x + (size_t)token * Din;

        float acc[8] = {0,0,0,0,0,0,0,0};
        #pragma unroll
        for (int i = 0; i < 4; i++) {
            float4 xv = *(const float4*)(xrow + i * 256 + lane * 4);
            #pragma unroll
            for (int e = 0; e < 8; e++) {
                float4 wv = *(const float4*)(s_rw + e * Din + i * 256 + lane * 4);
                acc[e] += xv.x * wv.x + xv.y * wv.y + xv.z * wv.z + xv.w * wv.w;
            }
        }
        #pragma unroll
        for (int e = 0; e < 8; e++) {
            #pragma unroll
            for (int m = 1; m < 64; m <<= 1) acc[e] += __shfl_xor(acc[e], m, 64);
        }

        float p[8], mx = -1e30f;
        #pragma unroll
        for (int e = 0; e < 8; e++) { p[e] = acc[e] + rbv[e]; mx = fmaxf(mx, p[e]); }
        float s = 0.f;
        #pragma unroll
        for (int e = 0; e < 8; e++) { p[e] = expf(p[e] - mx); s += p[e]; }
        float inv = 1.f / s;
        #pragma unroll
        for (int e = 0; e < 8; e++) p[e] *= inv;

        if (lane == 0) {
            float* po = probs_out + (size_t)token * Ecnt;
            #pragma unroll
            for (int e = 0; e < 8; e++) po[e] = p[e];
            int i0 = 0; float v0 = p[0];
            #pragma unroll
            for (int e = 1; e < 8; e++) if (p[e] > v0) { v0 = p[e]; i0 = e; }
            int i1 = -1; float v1 = -1e30f;
            #pragma unroll
            for (int e = 0; e < 8; e++) if (e != i0 && p[e] > v1) { v1 = p[e]; i1 = e; }
            float invs = 1.f / (v0 + v1);
            s_e[2 * li]     = i0;  s_g[2 * li]     = v0 * invs;
            s_e[2 * li + 1] = i1;  s_g[2 * li + 1] = v1 * invs;
        }
    }
    __syncthreads();

    if (t < 64) s_lpos[t] = atomicAdd(&s_lcnt[s_e[t]], 1);
    __syncthreads();
    if (t < Ecnt) s_base[t] = atomicAdd(&cnt[t * CNT_PAD], s_lcnt[t]);
    __syncthreads();
    if (t < 64) {
        int e = s_e[t];
        int pos = s_base[e] + s_lpos[t];
        int li = t >> 1;
        int token = blockIdx.x * 32 + li;
        bucket[e * Bsz + pos] = token * 2 + (t & 1);
        gates [e * Bsz + pos] = s_g[t];
    }
}

// ---------------- MFMA grouped GEMM: 128x128, A via LDS-dbuf, B direct global->reg ----------------
// R7 change: B never touches LDS. Within a block each wave owns a distinct 64-col n-range,
// so LDS-staging B has zero sharing value — it only added gload_lds writes, ds_reads, bank
// conflicts, and drain time. B frags are loaded global->reg (L2-resident after R6's
// expert-major XCD map), register-double-buffered one K-step ahead (named bA/bB sets,
// K-loop unrolled x2 — no dynamic frag indexing). A (gathered, shared by wave pairs)
// stays LDS double-buffered. LDS drops 33.8->~17 KB.
template<int Kd, bool G1>
__global__ __launch_bounds__(256) void moe_gemm(
    const f16* __restrict__ A, const f16* __restrict__ Wt,
    const float* __restrict__ bias, const int* __restrict__ cnt,
    const int* __restrict__ bucket, const float* __restrict__ gates,
    f16* __restrict__ hbuf, float* __restrict__ out, int Ndim)
{
    // expert-major XCD map (R6): e = bid%8 -> one expert per XCD, W[e] L2-resident;
    // n-block fastest -> gathered A-panel reused while L2-hot.
    int e   = (int)blockIdx.x & 7;
    int idx = (int)blockIdx.x >> 3;
    int nx  = Ndim >> 7;
    int by  = idx / nx;
    int bx  = idx - by * nx;

    int count = min(cnt[e * CNT_PAD], Bsz);
    int m0 = by * 128;
    if (m0 >= count) return;
    int n0 = bx * 128;

    __shared__ alignas(16) f16 As[2][128 * 32];   // 2 x 8 KiB (A only)
    __shared__ int   s_rows[128];
    __shared__ float s_gates[128];

    int t = threadIdx.x;
    if (t < 128) {
        int pos = min(m0 + t, count - 1);
        s_rows[t] = bucket[e * Bsz + pos];
        if constexpr (!G1) s_gates[t] = gates[e * Bsz + pos];
    }
    __syncthreads();

    int wave = t >> 6, lane = t & 63;
    int scol = (lane & 3) * 8;            // f16 elems within row (16 B chunks)

    // A staging pointers (2 gload_lds per thread per K-step)
    const f16* agp[2];
    #pragma unroll
    for (int j = 0; j < 2; j++) {
        int srow = wave * 32 + j * 16 + (lane >> 2);
        int r = s_rows[srow];
        size_t arow = G1 ? (size_t)(r >> 1) : (size_t)r;
        agp[j] = A + arow * Kd + scol;
    }

    int m_w = (wave >> 1) * 64;           // wave's 64x64 sub-tile
    int n_w = (wave & 1) * 64;
    int frow = lane & 15;
    int fk   = (lane >> 4) * 8;

    // B fragment pointers: lane reads 16 B of row (n0 + n_w + jj*16 + frow) at k-offset fk
    const f16* bp[4];
    #pragma unroll
    for (int jj = 0; jj < 4; jj++)
        bp[jj] = Wt + ((size_t)e * Ndim + (n0 + n_w + jj * 16 + frow)) * (size_t)Kd + fk;

    f32x4 acc[4][4] = {};
    f16x8 bA[4], bB[4];

    // ---- prologue: stage A(0) -> buf0; load B(0) -> bA ----
    #pragma unroll
    for (int j = 0; j < 2; j++) {
        async_copy16(agp[j], &As[0][(wave * 32 + j * 16) * 32]);
        agp[j] += 32;
    }
    #pragma unroll
    for (int jj = 0; jj < 4; jj++) { bA[jj] = *(const f16x8*)(bp[jj]); bp[jj] += 32; }
    __syncthreads();   // drains A-stage (and B loads) — tile 0 ready

    int cur = 0;
    for (int k0 = 0; k0 < Kd; k0 += 64) {
        // ===== sub-step 0: consume bA; prefetch A(k0+32)->LDS, B(k0+32)->bB =====
        f16x8 af[4];
        #pragma unroll
        for (int i = 0; i < 4; i++)
            af[i] = *(const f16x8*)(&As[cur][(m_w + i * 16 + frow) * 32 + fk]);
        #pragma unroll
        for (int j = 0; j < 2; j++) {        // k0+32 < Kd always (Kd % 64 == 0)
            async_copy16(agp[j], &As[cur ^ 1][(wave * 32 + j * 16) * 32]);
            agp[j] += 32;
        }
        #pragma unroll
        for (int jj = 0; jj < 4; jj++) { bB[jj] = *(const f16x8*)(bp[jj]); bp[jj] += 32; }
        __builtin_amdgcn_s_setprio(1);
        #pragma unroll
        for (int i = 0; i < 4; i++)
            #pragma unroll
            for (int jj = 0; jj < 4; jj++)
                acc[i][jj] = __builtin_amdgcn_mfma_f32_16x16x32_f16(
                    af[i], bA[jj], acc[i][jj], 0, 0, 0);
        __builtin_amdgcn_s_setprio(0);
        __syncthreads();
        cur ^= 1;

        // ===== sub-step 1: consume bB; prefetch A(k0+64)->LDS, B(k0+64)->bA =====
        #pragma unroll
        for (int i = 0; i < 4; i++)
            af[i] = *(const f16x8*)(&As[cur][(m_w + i * 16 + frow) * 32 + fk]);
        if (k0 + 64 < Kd) {
            #pragma unroll
            for (int j = 0; j < 2; j++) {
                async_copy16(agp[j], &As[cur ^ 1][(wave * 32 + j * 16) * 32]);
                agp[j] += 32;
            }
            #pragma unroll
            for (int jj = 0; jj < 4; jj++) { bA[jj] = *(const f16x8*)(bp[jj]); bp[jj] += 32; }
        }
        __builtin_amdgcn_s_setprio(1);
        #pragma unroll
        for (int i = 0; i < 4; i++)
            #pragma unroll
            for (int jj = 0; jj < 4; jj++)
                acc[i][jj] = __builtin_amdgcn_mfma_f32_16x16x32_f16(
                    af[i], bB[jj], acc[i][jj], 0, 0, 0);
        __builtin_amdgcn_s_setprio(0);
        __syncthreads();
        cur ^= 1;
    }

    // epilogue: D row = m = (lane>>4)*4 + reg (+16*i), D col = n = lane&15 (+16*jj)
    float bv[4];
    #pragma unroll
    for (int jj = 0; jj < 4; jj++)
        bv[jj] = bias[e * Ndim + n0 + n_w + jj * 16 + frow];

    #pragma unroll
    for (int i = 0; i < 4; i++) {
        int mbase = m_w + i * 16 + (lane >> 4) * 4;
        #pragma unroll
        for (int reg = 0; reg < 4; reg++) {
            int m = mbase + reg;
            if (m0 + m >= count) continue;
            int r = s_rows[m];
            if constexpr (G1) {
                f16* hrow = hbuf + (size_t)r * Hdim;
                #pragma unroll
                for (int jj = 0; jj < 4; jj++) {
                    int n = n0 + n_w + jj * 16 + frow;
                    float v = acc[i][jj][reg] + bv[jj];
                    hrow[n] = (f16)fmaxf(v, 0.f);
                }
            } else {
                int token = r >> 1;
                float g = s_gates[m];
                #pragma unroll
                for (int jj = 0; jj < 4; jj++) {
                    int n = n0 + n_w + jj * 16 + frow;
                    float v = g * (acc[i][jj][reg] + bv[jj]);
                    atomicAdd(&out[(size_t)token * Dout + n], v);
                }
            }
        }
    }
}

extern "C" void kernel_launch(void* const* d_in, const int* in_sizes, int n_in,
                              void* d_out, int out_size, void* d_ws, size_t ws_size,
                              hipStream_t stream) {
    const float* x   = (const float*)d_in[0];
    const float* rW  = (const float*)d_in[1];
    const float* rb  = (const float*)d_in[2];
    const float* W1  = (const float*)d_in[3];
    const float* b1  = (const float*)d_in[4];
    const float* W2  = (const float*)d_in[5];
    const float* b2  = (const float*)d_in[6];
    float* out   = (float*)d_out;
    float* probs = out + (size_t)Bsz * Dout;

    char* ws = (char*)d_ws;
    int*   cnt    = (int*)ws;                            // padded counters
    int*   bucket = (int*)(ws + 0x1000);                 // 512 KiB
    float* gates  = (float*)(ws + 0x90000);              // 512 KiB
    f16*   x16    = (f16*)(ws + 0x200000);               // 32 MiB
    f16*   w16    = (f16*)(ws + 0x2200000);              // 32 MiB (W1, then W2)
    f16*   hbuf   = (f16*)(ws + 0x4200000);              // 128 MiB

    hipMemsetAsync(cnt, 0, Ecnt * CNT_PAD * sizeof(int), stream);
    hipMemsetAsync(out, 0, (size_t)Bsz * Dout * sizeof(float), stream);

    cast_kernel<<<(Bsz * Din) / 1024, 256, 0, stream>>>(x, x16);
    cast_kernel<<<(Ecnt * Hdim * Din) / 1024, 256, 0, stream>>>(W1, w16);

    router_kernel<<<Bsz / 32, 256, 0, stream>>>(x, rW, rb, probs, cnt, bucket, gates);

    // expert-major 1-D grids: e = bid%8 (one expert per XCD), n-block fastest within expert
    int nb1 = Ecnt * (Bsz / 128) * (Hdim / 128);   // 16384
    moe_gemm<Din, true><<<nb1, 256, 0, stream>>>(
        x16, w16, b1, cnt, bucket, gates, hbuf, out, Hdim);

    cast_kernel<<<(Ecnt * Dout * Hdim) / 1024, 256, 0, stream>>>(W2, w16);

    int nb2 = Ecnt * (Bsz / 128) * (Dout / 128);   // 8192
    moe_gemm<Hdim, false><<<nb2, 256, 0, stream>>>(
        hbuf, w16, b2, cnt, bucket, gates, hbuf, out, Dout);
}

// Round 8
// 768.044 us; speedup vs baseline: 1.3286x; 1.3286x over previous
//
#include <hip/hip_runtime.h>
#include <hip/hip_bf16.h>

#define Bsz  16384
#define Din  1024
#define Dout 1024
#define Hdim 2048
#define Ecnt 8
#define CNT_PAD 32   // pad expert counters to 128 B apart

typedef _Float16 f16;
typedef _Float16 f16x8 __attribute__((ext_vector_type(8)));
typedef _Float16 f16x4 __attribute__((ext_vector_type(4)));
typedef float    f32x4 __attribute__((ext_vector_type(4)));

#define AS_GLOBAL __attribute__((address_space(1)))
#define AS_LDS    __attribute__((address_space(3)))

__device__ __forceinline__ void async_copy16(const void* gptr, void* lptr) {
    __builtin_amdgcn_global_load_lds(
        (const AS_GLOBAL unsigned int*)gptr,
        (AS_LDS unsigned int*)lptr, 16, 0, 0);
}

// ---------------- fp32 -> fp16 cast ----------------
__global__ __launch_bounds__(256) void cast_kernel(
    const float* __restrict__ in, f16* __restrict__ out)
{
    int i = (blockIdx.x * 256 + threadIdx.x) * 4;
    float4 v = *(const float4*)(in + i);
    f16x4 o;
    o.x = (f16)v.x; o.y = (f16)v.y; o.z = (f16)v.z; o.w = (f16)v.w;
    *(f16x4*)(out + i) = o;
}

// ---------------- Router: logits -> softmax -> top-2 -> buckets ----------------
__global__ __launch_bounds__(256) void router_kernel(
    const float* __restrict__ x, const float* __restrict__ rW,
    const float* __restrict__ rb, float* __restrict__ probs_out,
    int* __restrict__ cnt, int* __restrict__ bucket, float* __restrict__ gates)
{
    __shared__ float s_rw[Ecnt * Din];   // 32 KiB
    __shared__ int   s_e[64];
    __shared__ float s_g[64];
    __shared__ int   s_lpos[64];
    __shared__ int   s_lcnt[Ecnt];
    __shared__ int   s_base[Ecnt];

    int t = threadIdx.x;
    if (t < Ecnt) s_lcnt[t] = 0;
    for (int i = t; i < Ecnt * Din; i += 256) s_rw[i] = rW[i];
    __syncthreads();

    int wid = t >> 6, lane = t & 63;

    float rbv[8];
    #pragma unroll
    for (int e = 0; e < 8; e++) rbv[e] = rb[e];

    #pragma unroll 2
    for (int tt = 0; tt < 8; tt++) {
        int li = wid * 8 + tt;
        int token = blockIdx.x * 32 + li;
        const float* xrow = x + (size_t)token * Din;

        float acc[8] = {0,0,0,0,0,0,0,0};
        #pragma unroll
        for (int i = 0; i < 4; i++) {
            float4 xv = *(const float4*)(xrow + i * 256 + lane * 4);
            #pragma unroll
            for (int e = 0; e < 8; e++) {
                float4 wv = *(const float4*)(s_rw + e * Din + i * 256 + lane * 4);
                acc[e] += xv.x * wv.x + xv.y * wv.y + xv.z * wv.z + xv.w * wv.w;
            }
        }
        #pragma unroll
        for (int e = 0; e < 8; e++) {
            #pragma unroll
            for (int m = 1; m < 64; m <<= 1) acc[e] += __shfl_xor(acc[e], m, 64);
        }

        float p[8], mx = -1e30f;
        #pragma unroll
        for (int e = 0; e < 8; e++) { p[e] = acc[e] + rbv[e]; mx = fmaxf(mx, p[e]); }
        float s = 0.f;
        #pragma unroll
        for (int e = 0; e < 8; e++) { p[e] = expf(p[e] - mx); s += p[e]; }
        float inv = 1.f / s;
        #pragma unroll
        for (int e = 0; e < 8; e++) p[e] *= inv;

        if (lane == 0) {
            float* po = probs_out + (size_t)token * Ecnt;
            #pragma unroll
            for (int e = 0; e < 8; e++) po[e] = p[e];
            int i0 = 0; float v0 = p[0];
            #pragma unroll
            for (int e = 1; e < 8; e++) if (p[e] > v0) { v0 = p[e]; i0 = e; }
            int i1 = -1; float v1 = -1e30f;
            #pragma unroll
            for (int e = 0; e < 8; e++) if (e != i0 && p[e] > v1) { v1 = p[e]; i1 = e; }
            float invs = 1.f / (v0 + v1);
            s_e[2 * li]     = i0;  s_g[2 * li]     = v0 * invs;
            s_e[2 * li + 1] = i1;  s_g[2 * li + 1] = v1 * invs;
        }
    }
    __syncthreads();

    if (t < 64) s_lpos[t] = atomicAdd(&s_lcnt[s_e[t]], 1);
    __syncthreads();
    if (t < Ecnt) s_base[t] = atomicAdd(&cnt[t * CNT_PAD], s_lcnt[t]);
    __syncthreads();
    if (t < 64) {
        int e = s_e[t];
        int pos = s_base[e] + s_lpos[t];
        int li = t >> 1;
        int token = blockIdx.x * 32 + li;
        bucket[e * Bsz + pos] = token * 2 + (t & 1);
        gates [e * Bsz + pos] = s_g[t];
    }
}

// ---------------- MFMA grouped GEMM: 64x128 tile, 2 waves, LDS dbuf, 1 barrier/K-step ----------------
// R8 change vs R6 (265us G2): block = 2 waves / 64x128 tile instead of 4 waves / 128x128.
// Same per-wave 64x64 sub-tile and identical K-loop structure; LDS 33.8->24.6 KiB ->
// ~6 resident blocks/CU = 6 INDEPENDENT barrier domains (vs 2.5 of 4 ganged waves).
// When one block stalls on a first-touch HBM miss of its gathered A-panel, five other
// blocks keep the matrix pipe fed. B rows are now read by exactly one wave (no duplicate
// LDS reads for B). Expert-major XCD map retained (e = bid%8, n-fastest).
template<int Kd, bool G1>
__global__ __launch_bounds__(128) void moe_gemm(
    const f16* __restrict__ A, const f16* __restrict__ Wt,
    const float* __restrict__ bias, const int* __restrict__ cnt,
    const int* __restrict__ bucket, const float* __restrict__ gates,
    f16* __restrict__ hbuf, float* __restrict__ out, int Ndim)
{
    int e   = (int)blockIdx.x & 7;
    int idx = (int)blockIdx.x >> 3;
    int nx  = Ndim >> 7;               // 128-wide n-blocks per expert
    int by  = idx / nx;                // m-block (64 rows); n fastest for A-panel L2 reuse
    int bx  = idx - by * nx;

    int count = min(cnt[e * CNT_PAD], Bsz);
    int m0 = by * 64;
    if (m0 >= count) return;
    int n0 = bx * 128;

    __shared__ alignas(16) f16 As[2][64 * 32];    // 2 x 4 KiB
    __shared__ alignas(16) f16 Bs[2][128 * 32];   // 2 x 8 KiB
    __shared__ int   s_rows[64];
    __shared__ float s_gates[64];

    int t = threadIdx.x;
    if (t < 64) {
        int pos = min(m0 + t, count - 1);
        s_rows[t] = bucket[e * Bsz + pos];
        if constexpr (!G1) s_gates[t] = gates[e * Bsz + pos];
    }
    __syncthreads();

    int wave = t >> 6, lane = t & 63;
    int scol = (lane & 3) * 8;            // 16 B chunk within row

    // A staging: instruction q = wave*2+j covers rows q*16 + (lane>>2)  (64 rows x 32 k)
    const f16* agp[2];
    #pragma unroll
    for (int j = 0; j < 2; j++) {
        int srow = (wave * 2 + j) * 16 + (lane >> 2);
        int r = s_rows[srow];
        size_t arow = G1 ? (size_t)(r >> 1) : (size_t)r;
        agp[j] = A + arow * Kd + scol;
    }
    // B staging: instruction q = wave*4+j covers rows q*16 + (lane>>2)  (128 rows x 32 k)
    const f16* bgp[4];
    #pragma unroll
    for (int j = 0; j < 4; j++) {
        int srow = (wave * 4 + j) * 16 + (lane >> 2);
        bgp[j] = Wt + ((size_t)e * Ndim + (n0 + srow)) * (size_t)Kd + scol;
    }

    int n_w = wave * 64;                  // wave's 64-col n-range (m covers all 64 rows)
    int frow = lane & 15;
    int fk   = (lane >> 4) * 8;

    f32x4 acc[4][4] = {};

    // prologue: stage tile 0 into buffer 0
    #pragma unroll
    for (int j = 0; j < 2; j++) {
        async_copy16(agp[j], &As[0][(wave * 2 + j) * 512]);
        agp[j] += 32;
    }
    #pragma unroll
    for (int j = 0; j < 4; j++) {
        async_copy16(bgp[j], &Bs[0][(wave * 4 + j) * 512]);
        bgp[j] += 32;
    }
    __syncthreads();   // tile 0 resident

    int cur = 0;
    for (int k0 = 0; k0 < Kd; k0 += 32) {
        // 1) ds_reads of current buffer
        f16x8 af[4], bfr[4];
        #pragma unroll
        for (int i = 0; i < 4; i++)
            af[i]  = *(const f16x8*)(&As[cur][(i * 16 + frow) * 32 + fk]);
        #pragma unroll
        for (int jj = 0; jj < 4; jj++)
            bfr[jj] = *(const f16x8*)(&Bs[cur][(n_w + jj * 16 + frow) * 32 + fk]);
        // 2) prefetch next K-tile into the other buffer
        if (k0 + 32 < Kd) {
            #pragma unroll
            for (int j = 0; j < 2; j++) {
                async_copy16(agp[j], &As[cur ^ 1][(wave * 2 + j) * 512]);
                agp[j] += 32;
            }
            #pragma unroll
            for (int j = 0; j < 4; j++) {
                async_copy16(bgp[j], &Bs[cur ^ 1][(wave * 4 + j) * 512]);
                bgp[j] += 32;
            }
        }
        // 3) MFMA
        __builtin_amdgcn_s_setprio(1);
        #pragma unroll
        for (int i = 0; i < 4; i++)
            #pragma unroll
            for (int jj = 0; jj < 4; jj++)
                acc[i][jj] = __builtin_amdgcn_mfma_f32_16x16x32_f16(
                    af[i], bfr[jj], acc[i][jj], 0, 0, 0);
        __builtin_amdgcn_s_setprio(0);
        // 4) single barrier per K-step
        __syncthreads();
        cur ^= 1;
    }

    // epilogue: D row m = i*16 + (lane>>4)*4 + reg, col n = n0 + n_w + jj*16 + frow
    float bv[4];
    #pragma unroll
    for (int jj = 0; jj < 4; jj++)
        bv[jj] = bias[e * Ndim + n0 + n_w + jj * 16 + frow];

    #pragma unroll
    for (int i = 0; i < 4; i++) {
        int mbase = i * 16 + (lane >> 4) * 4;
        #pragma unroll
        for (int reg = 0; reg < 4; reg++) {
            int m = mbase + reg;
            if (m0 + m >= count) continue;
            int r = s_rows[m];
            if constexpr (G1) {
                f16* hrow = hbuf + (size_t)r * Hdim;
                #pragma unroll
                for (int jj = 0; jj < 4; jj++) {
                    int n = n0 + n_w + jj * 16 + frow;
                    float v = acc[i][jj][reg] + bv[jj];
                    hrow[n] = (f16)fmaxf(v, 0.f);
                }
            } else {
                int token = r >> 1;
                float g = s_gates[m];
                #pragma unroll
                for (int jj = 0; jj < 4; jj++) {
                    int n = n0 + n_w + jj * 16 + frow;
                    float v = g * (acc[i][jj][reg] + bv[jj]);
                    atomicAdd(&out[(size_t)token * Dout + n], v);
                }
            }
        }
    }
}

extern "C" void kernel_launch(void* const* d_in, const int* in_sizes, int n_in,
                              void* d_out, int out_size, void* d_ws, size_t ws_size,
                              hipStream_t stream) {
    const float* x   = (const float*)d_in[0];
    const float* rW  = (const float*)d_in[1];
    const float* rb  = (const float*)d_in[2];
    const float* W1  = (const float*)d_in[3];
    const float* b1  = (const float*)d_in[4];
    const float* W2  = (const float*)d_in[5];
    const float* b2  = (const float*)d_in[6];
    float* out   = (float*)d_out;
    float* probs = out + (size_t)Bsz * Dout;

    char* ws = (char*)d_ws;
    int*   cnt    = (int*)ws;                            // padded counters
    int*   bucket = (int*)(ws + 0x1000);                 // 512 KiB
    float* gates  = (float*)(ws + 0x90000);              // 512 KiB
    f16*   x16    = (f16*)(ws + 0x200000);               // 32 MiB
    f16*   w16    = (f16*)(ws + 0x2200000);              // 32 MiB (W1, then W2)
    f16*   hbuf   = (f16*)(ws + 0x4200000);              // 128 MiB

    hipMemsetAsync(cnt, 0, Ecnt * CNT_PAD * sizeof(int), stream);
    hipMemsetAsync(out, 0, (size_t)Bsz * Dout * sizeof(float), stream);

    cast_kernel<<<(Bsz * Din) / 1024, 256, 0, stream>>>(x, x16);
    cast_kernel<<<(Ecnt * Hdim * Din) / 1024, 256, 0, stream>>>(W1, w16);

    router_kernel<<<Bsz / 32, 256, 0, stream>>>(x, rW, rb, probs, cnt, bucket, gates);

    // expert-major 1-D grids: e = bid%8 (one expert per XCD), n-block fastest within expert
    int nb1 = Ecnt * (Bsz / 64) * (Hdim / 128);   // 32768
    moe_gemm<Din, true><<<nb1, 128, 0, stream>>>(
        x16, w16, b1, cnt, bucket, gates, hbuf, out, Hdim);

    cast_kernel<<<(Ecnt * Dout * Hdim) / 1024, 256, 0, stream>>>(W2, w16);

    int nb2 = Ecnt * (Bsz / 64) * (Dout / 128);   // 16384
    moe_gemm<Hdim, false><<<nb2, 128, 0, stream>>>(
        hbuf, w16, b2, cnt, bucket, gates, hbuf, out, Dout);
}

// Round 9
// 670.252 us; speedup vs baseline: 1.5224x; 1.1459x over previous
//
#include <hip/hip_runtime.h>
#include <hip/hip_bf16.h>

#define Bsz  16384
#define Din  1024
#define Dout 1024
#define Hdim 2048
#define Ecnt 8
#define CNT_PAD 32   // pad expert counters to 128 B apart

typedef _Float16 f16;
typedef _Float16 f16x8 __attribute__((ext_vector_type(8)));
typedef _Float16 f16x4 __attribute__((ext_vector_type(4)));
typedef float    f32x4 __attribute__((ext_vector_type(4)));

#define AS_GLOBAL __attribute__((address_space(1)))
#define AS_LDS    __attribute__((address_space(3)))

__device__ __forceinline__ void async_copy16(const void* gptr, void* lptr) {
    __builtin_amdgcn_global_load_lds(
        (const AS_GLOBAL unsigned int*)gptr,
        (AS_LDS unsigned int*)lptr, 16, 0, 0);
}

// ---------------- fp32 -> fp16 cast (W1 / W2 only; x fused into router) ----------------
__global__ __launch_bounds__(256) void cast_kernel(
    const float* __restrict__ in, f16* __restrict__ out)
{
    int i = (blockIdx.x * 256 + threadIdx.x) * 4;
    float4 v = *(const float4*)(in + i);
    f16x4 o;
    o.x = (f16)v.x; o.y = (f16)v.y; o.z = (f16)v.z; o.w = (f16)v.w;
    *(f16x4*)(out + i) = o;
}

// ---------------- Router: logits -> softmax -> top-2 -> buckets (+ fused x->f16 cast) ----------------
__global__ __launch_bounds__(256) void router_kernel(
    const float* __restrict__ x, const float* __restrict__ rW,
    const float* __restrict__ rb, float* __restrict__ probs_out,
    int* __restrict__ cnt, int* __restrict__ bucket, float* __restrict__ gates,
    f16* __restrict__ x16)
{
    __shared__ float s_rw[Ecnt * Din];   // 32 KiB
    __shared__ int   s_e[64];
    __shared__ float s_g[64];
    __shared__ int   s_lpos[64];
    __shared__ int   s_lcnt[Ecnt];
    __shared__ int   s_base[Ecnt];

    int t = threadIdx.x;
    if (t < Ecnt) s_lcnt[t] = 0;
    for (int i = t; i < Ecnt * Din; i += 256) s_rw[i] = rW[i];
    __syncthreads();

    int wid = t >> 6, lane = t & 63;

    float rbv[8];
    #pragma unroll
    for (int e = 0; e < 8; e++) rbv[e] = rb[e];

    #pragma unroll 2
    for (int tt = 0; tt < 8; tt++) {
        int li = wid * 8 + tt;
        int token = blockIdx.x * 32 + li;
        const float* xrow = x + (size_t)token * Din;
        f16* xorow = x16 + (size_t)token * Din;

        float acc[8] = {0,0,0,0,0,0,0,0};
        #pragma unroll
        for (int i = 0; i < 4; i++) {
            int d = i * 256 + lane * 4;
            float4 xv = *(const float4*)(xrow + d);
            // fused cast: this lane owns these 4 elems -> write f16 copy
            f16x4 xo;
            xo.x = (f16)xv.x; xo.y = (f16)xv.y; xo.z = (f16)xv.z; xo.w = (f16)xv.w;
            *(f16x4*)(xorow + d) = xo;
            #pragma unroll
            for (int e = 0; e < 8; e++) {
                float4 wv = *(const float4*)(s_rw + e * Din + d);
                acc[e] += xv.x * wv.x + xv.y * wv.y + xv.z * wv.z + xv.w * wv.w;
            }
        }
        #pragma unroll
        for (int e = 0; e < 8; e++) {
            #pragma unroll
            for (int m = 1; m < 64; m <<= 1) acc[e] += __shfl_xor(acc[e], m, 64);
        }

        float p[8], mx = -1e30f;
        #pragma unroll
        for (int e = 0; e < 8; e++) { p[e] = acc[e] + rbv[e]; mx = fmaxf(mx, p[e]); }
        float s = 0.f;
        #pragma unroll
        for (int e = 0; e < 8; e++) { p[e] = expf(p[e] - mx); s += p[e]; }
        float inv = 1.f / s;
        #pragma unroll
        for (int e = 0; e < 8; e++) p[e] *= inv;

        if (lane == 0) {
            float* po = probs_out + (size_t)token * Ecnt;
            #pragma unroll
            for (int e = 0; e < 8; e++) po[e] = p[e];
            int i0 = 0; float v0 = p[0];
            #pragma unroll
            for (int e = 1; e < 8; e++) if (p[e] > v0) { v0 = p[e]; i0 = e; }
            int i1 = -1; float v1 = -1e30f;
            #pragma unroll
            for (int e = 0; e < 8; e++) if (e != i0 && p[e] > v1) { v1 = p[e]; i1 = e; }
            float invs = 1.f / (v0 + v1);
            s_e[2 * li]     = i0;  s_g[2 * li]     = v0 * invs;
            s_e[2 * li + 1] = i1;  s_g[2 * li + 1] = v1 * invs;
        }
    }
    __syncthreads();

    if (t < 64) s_lpos[t] = atomicAdd(&s_lcnt[s_e[t]], 1);
    __syncthreads();
    if (t < Ecnt) s_base[t] = atomicAdd(&cnt[t * CNT_PAD], s_lcnt[t]);
    __syncthreads();
    if (t < 64) {
        int e = s_e[t];
        int pos = s_base[e] + s_lpos[t];
        int li = t >> 1;
        int token = blockIdx.x * 32 + li;
        bucket[e * Bsz + pos] = token * 2 + (t & 1);
        gates [e * Bsz + pos] = s_g[t];
    }
}

// ---------------- MFMA grouped GEMM: 128x128, LDS dbuf, STAGE-FIRST 2-phase (T3 order) ----------------
// R9 change vs R6 (265us G2): the K-loop issues the next-tile global_load_lds FIRST
// (immediately after the barrier), then ds_reads, then MFMA. Previously the stage was
// issued ~80cyc before the barrier's vmcnt(0) drain -> every K-step ate a near-full L2
// round-trip in the drain. Stage-first gives the loads the whole ds_read+lgkm+MFMA window
// (~400cyc) to land. WAR safe: the staged buffer's ds_reads completed before the PREVIOUS
// barrier. Expert-major XCD map retained (e = bid%8 -> W[e] L2-resident; n-fastest).
template<int Kd, bool G1>
__global__ __launch_bounds__(256) void moe_gemm(
    const f16* __restrict__ A, const f16* __restrict__ Wt,
    const float* __restrict__ bias, const int* __restrict__ cnt,
    const int* __restrict__ bucket, const float* __restrict__ gates,
    f16* __restrict__ hbuf, float* __restrict__ out, int Ndim)
{
    int e   = (int)blockIdx.x & 7;
    int idx = (int)blockIdx.x >> 3;
    int nx  = Ndim >> 7;
    int by  = idx / nx;
    int bx  = idx - by * nx;

    int count = min(cnt[e * CNT_PAD], Bsz);
    int m0 = by * 128;
    if (m0 >= count) return;
    int n0 = bx * 128;

    __shared__ alignas(16) f16 As[2][128 * 32];   // 2 x 8 KiB
    __shared__ alignas(16) f16 Bs[2][128 * 32];   // 2 x 8 KiB
    __shared__ int   s_rows[128];
    __shared__ float s_gates[128];

    int t = threadIdx.x;
    if (t < 128) {
        int pos = min(m0 + t, count - 1);
        s_rows[t] = bucket[e * Bsz + pos];
        if constexpr (!G1) s_gates[t] = gates[e * Bsz + pos];
    }
    __syncthreads();

    int wave = t >> 6, lane = t & 63;
    int scol = (lane & 3) * 8;            // 16 B chunk within row

    const f16* agp[2];
    const f16* bgp[2];
    #pragma unroll
    for (int j = 0; j < 2; j++) {
        int srow = wave * 32 + j * 16 + (lane >> 2);
        int r = s_rows[srow];
        size_t arow = G1 ? (size_t)(r >> 1) : (size_t)r;
        agp[j] = A + arow * Kd + scol;
        bgp[j] = Wt + ((size_t)e * Ndim + (n0 + srow)) * (size_t)Kd + scol;
    }

    int m_w = (wave >> 1) * 64;           // wave's 64x64 sub-tile
    int n_w = (wave & 1) * 64;
    int frow = lane & 15;
    int fk   = (lane >> 4) * 8;

    f32x4 acc[4][4] = {};

    // prologue: stage tile 0 into buffer 0
    #pragma unroll
    for (int j = 0; j < 2; j++) {
        async_copy16(agp[j], &As[0][(wave * 32 + j * 16) * 32]);
        async_copy16(bgp[j], &Bs[0][(wave * 32 + j * 16) * 32]);
        agp[j] += 32; bgp[j] += 32;
    }
    __syncthreads();   // tile 0 resident

    int cur = 0;
    for (int k0 = 0; k0 < Kd; k0 += 32) {
        // 1) STAGE FIRST (T3 ordering): issue next K-tile right after the barrier.
        //    Target buffer's last reads completed before the PREVIOUS barrier (WAR-safe).
        if (k0 + 32 < Kd) {
            #pragma unroll
            for (int j = 0; j < 2; j++) {
                async_copy16(agp[j], &As[cur ^ 1][(wave * 32 + j * 16) * 32]);
                async_copy16(bgp[j], &Bs[cur ^ 1][(wave * 32 + j * 16) * 32]);
                agp[j] += 32; bgp[j] += 32;
            }
        }
        // 2) ds_reads of current buffer (lgkmcnt-only wait; does not drain the stages)
        f16x8 af[4], bfr[4];
        #pragma unroll
        for (int i = 0; i < 4; i++) {
            af[i]  = *(const f16x8*)(&As[cur][(m_w + i * 16 + frow) * 32 + fk]);
            bfr[i] = *(const f16x8*)(&Bs[cur][(n_w + i * 16 + frow) * 32 + fk]);
        }
        // 3) MFMA
        __builtin_amdgcn_s_setprio(1);
        #pragma unroll
        for (int i = 0; i < 4; i++)
            #pragma unroll
            for (int jj = 0; jj < 4; jj++)
                acc[i][jj] = __builtin_amdgcn_mfma_f32_16x16x32_f16(
                    af[i], bfr[jj], acc[i][jj], 0, 0, 0);
        __builtin_amdgcn_s_setprio(0);
        // 4) single barrier per K-step (drains stages; by now they've had ~400cyc to land)
        __syncthreads();
        cur ^= 1;
    }

    // epilogue: D row = m = (lane>>4)*4 + reg (+16*i), D col = n = lane&15 (+16*jj)
    float bv[4];
    #pragma unroll
    for (int jj = 0; jj < 4; jj++)
        bv[jj] = bias[e * Ndim + n0 + n_w + jj * 16 + frow];

    #pragma unroll
    for (int i = 0; i < 4; i++) {
        int mbase = m_w + i * 16 + (lane >> 4) * 4;
        #pragma unroll
        for (int reg = 0; reg < 4; reg++) {
            int m = mbase + reg;
            if (m0 + m >= count) continue;
            int r = s_rows[m];
            if constexpr (G1) {
                f16* hrow = hbuf + (size_t)r * Hdim;
                #pragma unroll
                for (int jj = 0; jj < 4; jj++) {
                    int n = n0 + n_w + jj * 16 + frow;
                    float v = acc[i][jj][reg] + bv[jj];
                    hrow[n] = (f16)fmaxf(v, 0.f);
                }
            } else {
                int token = r >> 1;
                float g = s_gates[m];
                #pragma unroll
                for (int jj = 0; jj < 4; jj++) {
                    int n = n0 + n_w + jj * 16 + frow;
                    float v = g * (acc[i][jj][reg] + bv[jj]);
                    atomicAdd(&out[(size_t)token * Dout + n], v);
                }
            }
        }
    }
}

extern "C" void kernel_launch(void* const* d_in, const int* in_sizes, int n_in,
                              void* d_out, int out_size, void* d_ws, size_t ws_size,
                              hipStream_t stream) {
    const float* x   = (const float*)d_in[0];
    const float* rW  = (const float*)d_in[1];
    const float* rb  = (const float*)d_in[2];
    const float* W1  = (const float*)d_in[3];
    const float* b1  = (const float*)d_in[4];
    const float* W2  = (const float*)d_in[5];
    const float* b2  = (const float*)d_in[6];
    float* out   = (float*)d_out;
    float* probs = out + (size_t)Bsz * Dout;

    char* ws = (char*)d_ws;
    int*   cnt    = (int*)ws;                            // padded counters
    int*   bucket = (int*)(ws + 0x1000);                 // 512 KiB
    float* gates  = (float*)(ws + 0x90000);              // 512 KiB
    f16*   x16    = (f16*)(ws + 0x200000);               // 32 MiB
    f16*   w16    = (f16*)(ws + 0x2200000);              // 32 MiB (W1, then W2)
    f16*   hbuf   = (f16*)(ws + 0x4200000);              // 128 MiB

    hipMemsetAsync(cnt, 0, Ecnt * CNT_PAD * sizeof(int), stream);
    hipMemsetAsync(out, 0, (size_t)Bsz * Dout * sizeof(float), stream);

    cast_kernel<<<(Ecnt * Hdim * Din) / 1024, 256, 0, stream>>>(W1, w16);

    // router also writes x16 (fused cast — x is read here anyway)
    router_kernel<<<Bsz / 32, 256, 0, stream>>>(x, rW, rb, probs, cnt, bucket, gates, x16);

    // expert-major 1-D grids: e = bid%8 (one expert per XCD), n-block fastest within expert
    int nb1 = Ecnt * (Bsz / 128) * (Hdim / 128);   // 16384
    moe_gemm<Din, true><<<nb1, 256, 0, stream>>>(
        x16, w16, b1, cnt, bucket, gates, hbuf, out, Hdim);

    cast_kernel<<<(Ecnt * Dout * Hdim) / 1024, 256, 0, stream>>>(W2, w16);

    int nb2 = Ecnt * (Bsz / 128) * (Dout / 128);   // 8192
    moe_gemm<Hdim, false><<<nb2, 256, 0, stream>>>(
        hbuf, w16, b2, cnt, bucket, gates, hbuf, out, Dout);
}